// Round 1
// 297.346 us; speedup vs baseline: 1.0052x; 1.0052x over previous
//
#include <hip/hip_runtime.h>

typedef short bf16x8 __attribute__((ext_vector_type(8)));
typedef float f32x4 __attribute__((ext_vector_type(4)));
typedef unsigned short u16x8 __attribute__((ext_vector_type(8)));

#define MASK_NEG (-1e30f)

__device__ __forceinline__ unsigned short f2bf(float f) {
  union { float f; unsigned u; } v; v.f = f;
  unsigned r = v.u + 0x7fffu + ((v.u >> 16) & 1u);
  return (unsigned short)(r >> 16);
}

__device__ __forceinline__ float bf2f(unsigned short u) {
  union { unsigned u; float f; } v; v.u = ((unsigned)u) << 16;
  return v.f;
}

__device__ __forceinline__ void gl_lds16(const void* g, void* l) {
  __builtin_amdgcn_global_load_lds(
      (__attribute__((address_space(1))) void*)(void*)g,
      (__attribute__((address_space(3))) void*)l, 16, 0, 0);
}

// -------- shared transpose body: dst[c][r] = bf16(src[r][c]), 64x64 tile ----
__device__ __forceinline__ void transpose_tile(
    const float* __restrict__ s, unsigned short* __restrict__ d,
    int R, int C, int x0, int y0, int t, float tile[64][65]) {
  {
    const int r = t >> 4, c4 = (t & 15) * 4;
    for (int it = 0; it < 4; ++it) {
      const int rr = r + it * 16;
      const float4 v = *(const float4*)(s + (size_t)(y0 + rr) * C + x0 + c4);
      tile[rr][c4 + 0] = v.x; tile[rr][c4 + 1] = v.y;
      tile[rr][c4 + 2] = v.z; tile[rr][c4 + 3] = v.w;
    }
  }
  __syncthreads();
  {
    const int cc = t >> 4, r4 = (t & 15) * 4;
    for (int it = 0; it < 4; ++it) {
      const int c = cc + it * 16;
      ushort4 o;
      o.x = f2bf(tile[r4 + 0][c]); o.y = f2bf(tile[r4 + 1][c]);
      o.z = f2bf(tile[r4 + 2][c]); o.w = f2bf(tile[r4 + 3][c]);
      *(ushort4*)(d + (size_t)(x0 + c) * R + y0 + r4) = o;
    }
  }
}

// -------- transpose x (8 batches) + Wo, all 1024x1024, one dispatch --------
__global__ __launch_bounds__(256) void transpose_x_wo(
    const float* __restrict__ x, const float* __restrict__ Wo,
    unsigned short* __restrict__ xt, unsigned short* __restrict__ Wot) {
  __shared__ float tile[64][65];
  const int z = blockIdx.z;   // 0..7: x batch, 8: Wo
  const float* s = (z < 8) ? (x + (size_t)z * 1048576) : Wo;
  unsigned short* d = (z < 8) ? (xt + (size_t)z * 1048576) : Wot;
  transpose_tile(s, d, 1024, 1024, blockIdx.x * 64, blockIdx.y * 64,
                 threadIdx.x, tile);
}

// -------- transpose all 24 per-head W matrices (1024x128) in one dispatch ---
__global__ __launch_bounds__(256) void transpose_w24(
    const float* __restrict__ Wq, const float* __restrict__ Wk,
    const float* __restrict__ Wv, unsigned short* __restrict__ WqkvT) {
  __shared__ float tile[64][65];
  const int z = blockIdx.z;   // 0..23
  const int sel = z >> 3, h = z & 7;
  const float* base = (sel == 0) ? Wq : (sel == 1) ? Wk : Wv;
  const float* s = base + (size_t)h * 131072;
  unsigned short* d = WqkvT + (size_t)z * 131072;
  transpose_tile(s, d, 1024, 128, blockIdx.x * 64, blockIdx.y * 64,
                 threadIdx.x, tile);
}

// -------- generic bf16 MFMA GEMM, BK=64 (m97 staging, scatter epilogue) -----
// C[M,N] = scale * A[M,K] * B[N,K]^T ; A,B K-contiguous; K % 64 == 0.
template<bool F32OUT>
__global__ __launch_bounds__(256) void gemm_tn(
    const unsigned short* __restrict__ A, const unsigned short* __restrict__ B,
    void* __restrict__ Cv,
    int K, int ldA, int ldB, int ldC, float scale,
    long sAl, long sAb, long sAh,
    long sBl, long sBb, long sBh,
    long sCl, long sCb, long sCh,
    int zbase, int zdiv)
{
  __shared__ unsigned short As[128 * 64];   // [128 rows][64 k], chunk-swizzled
  __shared__ unsigned short Bs[128 * 64];
  const int z = blockIdx.z;
  const int g = zbase + z;
  const int gb = g / zdiv, gh = g % zdiv;
  const unsigned short* Ab = A + (size_t)z * sAl + (size_t)gb * sAb + (size_t)gh * sAh;
  const unsigned short* Bb = B + (size_t)z * sBl + (size_t)gb * sBb + (size_t)gh * sBh;
  const int m0 = blockIdx.y * 128, n0 = blockIdx.x * 128;
  const int t = threadIdx.x;
  const int lane = t & 63;
  const int wave = t >> 6;
  const int wm = wave >> 1, wn = wave & 1;

  // staging: thread t fetches one 16B chunk per 32-row group.
  // row = c*32 + (t>>3); dst slot ss8 = t&7; source chunk sq8 = ss8 ^ (row&7).
  const int sr2 = t >> 3;          // 0..31
  const int ss8 = t & 7;
  const int sq8 = ss8 ^ (sr2 & 7); // row&7 == sr2&7 (32 | 8)

  const unsigned short* ap0 = Ab + (size_t)(m0 +  0 + sr2) * ldA + sq8 * 8;
  const unsigned short* ap1 = Ab + (size_t)(m0 + 32 + sr2) * ldA + sq8 * 8;
  const unsigned short* ap2 = Ab + (size_t)(m0 + 64 + sr2) * ldA + sq8 * 8;
  const unsigned short* ap3 = Ab + (size_t)(m0 + 96 + sr2) * ldA + sq8 * 8;
  const unsigned short* bp0 = Bb + (size_t)(n0 +  0 + sr2) * ldB + sq8 * 8;
  const unsigned short* bp1 = Bb + (size_t)(n0 + 32 + sr2) * ldB + sq8 * 8;
  const unsigned short* bp2 = Bb + (size_t)(n0 + 64 + sr2) * ldB + sq8 * 8;
  const unsigned short* bp3 = Bb + (size_t)(n0 + 96 + sr2) * ldB + sq8 * 8;

  char* asd0 = (char*)As +     0 + t * 16;
  char* asd1 = (char*)As +  4096 + t * 16;
  char* asd2 = (char*)As +  8192 + t * 16;
  char* asd3 = (char*)As + 12288 + t * 16;
  char* bsd0 = (char*)Bs +     0 + t * 16;
  char* bsd1 = (char*)Bs +  4096 + t * 16;
  char* bsd2 = (char*)Bs +  8192 + t * 16;
  char* bsd3 = (char*)Bs + 12288 + t * 16;

  const int tq = lane & 15, qd = lane >> 4;

  f32x4 acc[4][4];
  #pragma unroll
  for (int i = 0; i < 4; ++i)
    #pragma unroll
    for (int j = 0; j < 4; ++j)
      acc[i][j] = f32x4{0.f, 0.f, 0.f, 0.f};

  const int kIters = K >> 6;
  for (int kt = 0; kt < kIters; ++kt) {
    __syncthreads();
    gl_lds16(ap0, asd0); gl_lds16(ap1, asd1);
    gl_lds16(ap2, asd2); gl_lds16(ap3, asd3);
    gl_lds16(bp0, bsd0); gl_lds16(bp1, bsd1);
    gl_lds16(bp2, bsd2); gl_lds16(bp3, bsd3);
    ap0 += 64; ap1 += 64; ap2 += 64; ap3 += 64;
    bp0 += 64; bp1 += 64; bp2 += 64; bp3 += 64;
    __builtin_amdgcn_s_waitcnt(0x0f70);    // vmcnt(0)
    __syncthreads();

    #pragma unroll
    for (int kk = 0; kk < 2; ++kk) {
      bf16x8 af[4], bfr[4];
      #pragma unroll
      for (int i = 0; i < 4; ++i) {
        const int R = wm * 64 + i * 16 + tq;
        const int slot = (kk * 4 + qd) ^ (R & 7);
        af[i] = *(const bf16x8*)(As + R * 64 + slot * 8);
      }
      #pragma unroll
      for (int j = 0; j < 4; ++j) {
        const int R = wn * 64 + j * 16 + tq;
        const int slot = (kk * 4 + qd) ^ (R & 7);
        bfr[j] = *(const bf16x8*)(Bs + R * 64 + slot * 8);
      }
      #pragma unroll
      for (int i = 0; i < 4; ++i)
        #pragma unroll
        for (int j = 0; j < 4; ++j)
          acc[i][j] = __builtin_amdgcn_mfma_f32_16x16x32_bf16(af[i], bfr[j], acc[i][j], 0, 0, 0);
    }
  }

  const size_t cOff = (size_t)z * sCl + (size_t)gb * sCb + (size_t)gh * sCh;
  #pragma unroll
  for (int i = 0; i < 4; ++i) {
    const int row = m0 + wm * 64 + i * 16 + qd * 4;   // C/D: row=(lane>>4)*4+reg
    #pragma unroll
    for (int j = 0; j < 4; ++j) {
      const int col = n0 + wn * 64 + j * 16 + tq;     // C/D: col=lane&15
      if constexpr (F32OUT) {
        float* C = (float*)Cv + cOff;
        #pragma unroll
        for (int rr = 0; rr < 4; ++rr)
          C[(size_t)(row + rr) * ldC + col] = acc[i][j][rr] * scale;
      } else {
        unsigned short* C = (unsigned short*)Cv + cOff;
        #pragma unroll
        for (int rr = 0; rr < 4; ++rr)
          C[(size_t)(row + rr) * ldC + col] = f2bf(acc[i][j][rr] * scale);
      }
    }
  }
}

// -------- scores GEMM with fused mask + exp + query-axis column sums --------
// E[q][k] = exp(scale*Q[q,:].K[k,:] + (1-mask[b,q])*NEG - 20), bf16, per bh.
// colsum[bh][k] += sum_q E (fp32 atomics).
// Round-3 structure: single-stage K=128 (1 barrier round instead of 4),
// 16-slot XOR-swizzled LDS, epilogue repacked through LDS for coalesced
// ushort8 global stores (was 64 scalar short stores/thread).
__global__ __launch_bounds__(256) void gemm_scores_fused(
    const unsigned short* __restrict__ QKV,
    unsigned short* __restrict__ E, float* __restrict__ colsum,
    const float* __restrict__ mask, int zbase)
{
  __shared__ unsigned short sbuf[32768];   // 64 KB: As[128][128] | Bs[128][128]
  unsigned short* As = sbuf;               // reused as [128][136] E tile later
  unsigned short* Bs = sbuf + 16384;
  const int z = blockIdx.z;
  const int g = zbase + z;
  const int b = g >> 3, h = g & 7;
  const unsigned short* Ab = QKV + (size_t)b * 3145728 + (size_t)h * 131072;
  const unsigned short* Bb = Ab + 1048576;
  const int m0 = blockIdx.y * 128, n0 = blockIdx.x * 128;
  const int t = threadIdx.x;
  const int lane = t & 63;
  const int wave = t >> 6;
  const int wm = wave >> 1, wn = wave & 1;
  const int tq = lane & 15, qd = lane >> 4;

  // ---- single-shot staging of full 128x128 A and B tiles ----
  // chunk c (16B) -> LDS linear [row=c>>4][slot=c&15]; global source chunk
  // is slot ^ (row&15) so that a later read of slot' = q ^ (row&15) yields
  // k-chunk q conflict-free.
  const unsigned short* Aq = Ab + (size_t)m0 * 128;
  const unsigned short* Bk = Bb + (size_t)n0 * 128;
  #pragma unroll
  for (int it = 0; it < 8; ++it) {
    const int c = it * 256 + t;             // 0..2047
    const int row = c >> 4;
    const int src = (c ^ (c >> 4)) & 15;    // slot ^ (row&15)
    gl_lds16(Aq + (size_t)row * 128 + src * 8, (char*)As + c * 16);
    gl_lds16(Bk + (size_t)row * 128 + src * 8, (char*)Bs + c * 16);
  }
  __builtin_amdgcn_s_waitcnt(0x0f70);    // vmcnt(0)
  __syncthreads();

  f32x4 acc[4][4];
  #pragma unroll
  for (int i = 0; i < 4; ++i)
    #pragma unroll
    for (int j = 0; j < 4; ++j)
      acc[i][j] = f32x4{0.f, 0.f, 0.f, 0.f};

  #pragma unroll
  for (int kk = 0; kk < 4; ++kk) {
    bf16x8 af[4], bfr[4];
    #pragma unroll
    for (int i = 0; i < 4; ++i) {
      const int R = wm * 64 + i * 16 + tq;
      const int slot = (kk * 4 + qd) ^ (R & 15);
      af[i] = *(const bf16x8*)(As + R * 128 + slot * 8);
    }
    #pragma unroll
    for (int j = 0; j < 4; ++j) {
      const int R = wn * 64 + j * 16 + tq;
      const int slot = (kk * 4 + qd) ^ (R & 15);
      bfr[j] = *(const bf16x8*)(Bs + R * 128 + slot * 8);
    }
    #pragma unroll
    for (int i = 0; i < 4; ++i)
      #pragma unroll
      for (int j = 0; j < 4; ++j)
        acc[i][j] = __builtin_amdgcn_mfma_f32_16x16x32_bf16(af[i], bfr[j], acc[i][j], 0, 0, 0);
  }

  __syncthreads();   // all LDS frag reads done; sbuf is now the E-tile buffer

  // ---- fused mask+exp, scatter bf16 into LDS tile [128][136] ----
  unsigned short* T = sbuf;
  float* cs = colsum + (size_t)g * 1024;
  const float scl = 0.08838834764831845f;  // 1/sqrt(128)
  const float* mrow = mask + (size_t)b * 1024;

  float cp[4] = {0.f, 0.f, 0.f, 0.f};   // per-j partial column sums
  #pragma unroll
  for (int i = 0; i < 4; ++i) {
    const int r0 = wm * 64 + i * 16 + qd * 4;          // local q row base
    const float4 m4 = *(const float4*)(mrow + m0 + r0);
    const float aq[4] = {(1.f - m4.x) * MASK_NEG - 20.f, (1.f - m4.y) * MASK_NEG - 20.f,
                         (1.f - m4.z) * MASK_NEG - 20.f, (1.f - m4.w) * MASK_NEG - 20.f};
    #pragma unroll
    for (int rr = 0; rr < 4; ++rr) {
      #pragma unroll
      for (int j = 0; j < 4; ++j) {
        const int cl = wn * 64 + j * 16 + tq;
        const float e = __expf(acc[i][j][rr] * scl + aq[rr]);
        cp[j] += e;
        T[(r0 + rr) * 136 + cl] = f2bf(e);
      }
    }
  }
  #pragma unroll
  for (int j = 0; j < 4; ++j) {
    float v = cp[j];
    v += __shfl_xor(v, 16, 64);
    v += __shfl_xor(v, 32, 64);
    if (qd == 0)
      atomicAdd(&cs[n0 + wn * 64 + j * 16 + tq], v);
  }
  __syncthreads();

  // ---- coalesced E store: ushort8 per lane, contiguous 256B rows ----
  unsigned short* Ep = E + (size_t)z * 1048576 + (size_t)m0 * 1024 + n0;
  #pragma unroll
  for (int r = 0; r < 8; ++r) {
    const int c = r * 256 + t;              // 0..2047
    const int row = c >> 4, sl = c & 15;
    u16x8 v = *(const u16x8*)(T + row * 136 + sl * 8);
    *(u16x8*)(Ep + (size_t)row * 1024 + sl * 8) = v;
  }
}

// -------- transpose V [l][dv] -> V' [dv][l], scaled by 1/colsum[l] --------
__global__ __launch_bounds__(256) void tvscale(
    const unsigned short* __restrict__ QKV, unsigned short* __restrict__ Vp,
    const float* __restrict__ colsum, int zbase)
{
  __shared__ unsigned short tile[64][72];
  const int z = blockIdx.z;
  const int g = zbase + z;
  const int b = g >> 3, h = g & 7;
  const unsigned short* S = QKV + (size_t)b * 3145728 + (size_t)(16 + h) * 131072;
  unsigned short* D = Vp + (size_t)g * 131072;
  const float* cs = colsum + (size_t)g * 1024;
  const int l0 = blockIdx.x * 64;   // 16 tiles
  const int d0 = blockIdx.y * 64;   // 2 tiles
  const int t = threadIdx.x;
  {
    const int r = t >> 4, c4 = (t & 15) * 4;
    for (int it = 0; it < 4; ++it) {
      const int rr = r + it * 16;
      const ushort4 v = *(const ushort4*)(S + (size_t)(l0 + rr) * 128 + d0 + c4);
      *(ushort4*)&tile[rr][c4] = v;
    }
  }
  __syncthreads();
  {
    const int cc = t >> 4, r4 = (t & 15) * 4;
    const float4 c4v = *(const float4*)(cs + l0 + r4);
    for (int it = 0; it < 4; ++it) {
      const int c = cc + it * 16;   // dv
      ushort4 o;
      o.x = f2bf(bf2f(tile[r4 + 0][c]) / c4v.x);
      o.y = f2bf(bf2f(tile[r4 + 1][c]) / c4v.y);
      o.z = f2bf(bf2f(tile[r4 + 2][c]) / c4v.z);
      o.w = f2bf(bf2f(tile[r4 + 3][c]) / c4v.w);
      *(ushort4*)(D + (size_t)(d0 + c) * 1024 + l0 + r4) = o;
    }
  }
}

extern "C" void kernel_launch(void* const* d_in, const int* in_sizes, int n_in,
                              void* d_out, int out_size, void* d_ws, size_t ws_size,
                              hipStream_t stream) {
  const float* x    = (const float*)d_in[0];   // [8,1024,1024]  (B,D,L)
  const float* mask = (const float*)d_in[1];   // [8,1024]
  const float* Wq   = (const float*)d_in[2];   // [8,1024,128]
  const float* Wk   = (const float*)d_in[3];
  const float* Wv   = (const float*)d_in[4];
  const float* Wo   = (const float*)d_in[5];   // [1024,1024]
  float* out = (float*)d_out;                  // [8,1024,1024]  (B,D,L)

  char* p = (char*)d_ws;
  unsigned short* xt    = (unsigned short*)p; p += 16777216;  // [b][l][d] bf16
  unsigned short* WqkvT = (unsigned short*)p; p += 6291456;   // [24 heads][128][1024]
  unsigned short* Wot   = (unsigned short*)p; p += 2097152;   // [j][i]
  unsigned short* QKV   = (unsigned short*)p; p += 50331648;  // [b][24h][l][128]
  unsigned short* Vp    = (unsigned short*)p; p += 16777216;  // [b][h][dv][k]
  unsigned short* Hp    = (unsigned short*)p; p += 16777216;  // [b][l][h*128+dv]
  float* colsum = (float*)p; p += 262144;                     // [64][1024] fp32
  const size_t fixedBytes = (size_t)(p - (char*)d_ws);

  long nbh = 1;
  if (ws_size > fixedBytes) {
    nbh = (long)((ws_size - fixedBytes) / 2097152);
    if (nbh < 1) nbh = 1;
    if (nbh > 64) nbh = 64;
  }
  unsigned short* Ep = (unsigned short*)p;   // nbh x [q][k] bf16 (unnormalized exp)

  hipMemsetAsync(colsum, 0, 262144, stream);

  // prologue: transposes (2 dispatches instead of 5)
  transpose_x_wo<<<dim3(16, 16, 9), 256, 0, stream>>>(x, Wo, xt, Wot);
  transpose_w24<<<dim3(2, 16, 24), 256, 0, stream>>>(Wq, Wk, Wv, WqkvT);

  // QKV[b][gh][l][dk] = xt[b] * WqkvT[gh]^T   (z=192: gb=b, gh=0..23; 1536 blocks)
  gemm_tn<false><<<dim3(1, 8, 192), 256, 0, stream>>>(
      xt, WqkvT, (void*)QKV, 1024, 1024, 1024, 128, 1.f,
      0L, 1048576L, 0L,  0L, 0L, 131072L,  0L, 3145728L, 131072L, 0, 24);

  for (int s0 = 0; s0 < 64; s0 += (int)nbh) {
    const int cnt = (int)(((64 - s0) < nbh) ? (64 - s0) : nbh);
    // E + colsum (single-stage, coalesced stores)
    gemm_scores_fused<<<dim3(8, 8, cnt), 256, 0, stream>>>(QKV, Ep, colsum, mask, s0);
    // V' = V^T / colsum (transpose fused with normalization)
    tvscale<<<dim3(16, 2, cnt), 256, 0, stream>>>(QKV, Vp, colsum, s0);
    // H[b][q][h*128+dv] = E[q,:] . V'[dv,:]   (M=1024 q, N=128 dv, K=1024 k)
    gemm_tn<false><<<dim3(1, 8, cnt), 256, 0, stream>>>(
        Ep, Vp, (void*)Hp, 1024, 1024, 1024, 1024, 1.f,
        1048576L, 0L, 0L,  0L, 1048576L, 131072L,  0L, 1048576L, 128L, s0, 8);
  }
  // out[b][j][l] = Wot[j,:] . H[b][l,:]   (M=1024 j, N=1024 l, K=1024 i)
  gemm_tn<true><<<dim3(8, 8, 8), 256, 0, stream>>>(
      Wot, Hp, (void*)out, 1024, 1024, 1024, 1024, 1.f,
      0L, 0L, 0L,  0L, 1048576L, 0L,  0L, 1048576L, 0L, 0, 1);
}

// Round 2
// 276.216 us; speedup vs baseline: 1.0821x; 1.0765x over previous
//
#include <hip/hip_runtime.h>

typedef short bf16x8 __attribute__((ext_vector_type(8)));
typedef float f32x4 __attribute__((ext_vector_type(4)));

#define MASK_NEG (-1e30f)

__device__ __forceinline__ unsigned short f2bf(float f) {
  union { float f; unsigned u; } v; v.f = f;
  unsigned r = v.u + 0x7fffu + ((v.u >> 16) & 1u);
  return (unsigned short)(r >> 16);
}

__device__ __forceinline__ float bf2f(unsigned short u) {
  union { unsigned u; float f; } v; v.u = ((unsigned)u) << 16;
  return v.f;
}

__device__ __forceinline__ void gl_lds16(const void* g, void* l) {
  __builtin_amdgcn_global_load_lds(
      (__attribute__((address_space(1))) void*)(void*)g,
      (__attribute__((address_space(3))) void*)l, 16, 0, 0);
}

// -------- shared transpose body: dst[c][r] = bf16(src[r][c]), 64x64 tile ----
__device__ __forceinline__ void transpose_tile(
    const float* __restrict__ s, unsigned short* __restrict__ d,
    int R, int C, int x0, int y0, int t, float tile[64][65]) {
  {
    const int r = t >> 4, c4 = (t & 15) * 4;
    for (int it = 0; it < 4; ++it) {
      const int rr = r + it * 16;
      const float4 v = *(const float4*)(s + (size_t)(y0 + rr) * C + x0 + c4);
      tile[rr][c4 + 0] = v.x; tile[rr][c4 + 1] = v.y;
      tile[rr][c4 + 2] = v.z; tile[rr][c4 + 3] = v.w;
    }
  }
  __syncthreads();
  {
    const int cc = t >> 4, r4 = (t & 15) * 4;
    for (int it = 0; it < 4; ++it) {
      const int c = cc + it * 16;
      ushort4 o;
      o.x = f2bf(tile[r4 + 0][c]); o.y = f2bf(tile[r4 + 1][c]);
      o.z = f2bf(tile[r4 + 2][c]); o.w = f2bf(tile[r4 + 3][c]);
      *(ushort4*)(d + (size_t)(x0 + c) * R + y0 + r4) = o;
    }
  }
}

// -------- transpose x (8 batches) + Wo, all 1024x1024, one dispatch --------
__global__ __launch_bounds__(256) void transpose_x_wo(
    const float* __restrict__ x, const float* __restrict__ Wo,
    unsigned short* __restrict__ xt, unsigned short* __restrict__ Wot) {
  __shared__ float tile[64][65];
  const int z = blockIdx.z;   // 0..7: x batch, 8: Wo
  const float* s = (z < 8) ? (x + (size_t)z * 1048576) : Wo;
  unsigned short* d = (z < 8) ? (xt + (size_t)z * 1048576) : Wot;
  transpose_tile(s, d, 1024, 1024, blockIdx.x * 64, blockIdx.y * 64,
                 threadIdx.x, tile);
}

// -------- transpose all 24 per-head W matrices (1024x128) in one dispatch ---
__global__ __launch_bounds__(256) void transpose_w24(
    const float* __restrict__ Wq, const float* __restrict__ Wk,
    const float* __restrict__ Wv, unsigned short* __restrict__ WqkvT) {
  __shared__ float tile[64][65];
  const int z = blockIdx.z;   // 0..23
  const int sel = z >> 3, h = z & 7;
  const float* base = (sel == 0) ? Wq : (sel == 1) ? Wk : Wv;
  const float* s = base + (size_t)h * 131072;
  unsigned short* d = WqkvT + (size_t)z * 131072;
  transpose_tile(s, d, 1024, 128, blockIdx.x * 64, blockIdx.y * 64,
                 threadIdx.x, tile);
}

// -------- generic bf16 MFMA GEMM, BK=64 (m97 staging, scatter epilogue) -----
// C[M,N] = scale * A[M,K] * B[N,K]^T ; A,B K-contiguous; K % 64 == 0.
// Chunked XCD swizzle applied when nwg % 8 == 0 (T1).
template<bool F32OUT>
__global__ __launch_bounds__(256) void gemm_tn(
    const unsigned short* __restrict__ A, const unsigned short* __restrict__ B,
    void* __restrict__ Cv,
    int K, int ldA, int ldB, int ldC, float scale,
    long sAl, long sAb, long sAh,
    long sBl, long sBb, long sBh,
    long sCl, long sCb, long sCh,
    int zbase, int zdiv)
{
  __shared__ unsigned short As[128 * 64];   // [128 rows][64 k], chunk-swizzled
  __shared__ unsigned short Bs[128 * 64];
  // ---- chunked XCD swizzle: XCD i gets a contiguous work chunk ----
  int bx, by, bz;
  {
    const int nx = gridDim.x, ny = gridDim.y;
    const int nwg = nx * ny * gridDim.z;
    int flat = blockIdx.x + nx * (blockIdx.y + ny * blockIdx.z);
    if ((nwg & 7) == 0) flat = (flat & 7) * (nwg >> 3) + (flat >> 3);
    bx = flat % nx; flat /= nx;
    by = flat % ny; bz = flat / ny;
  }
  const int z = bz;
  const int g = zbase + z;
  const int gb = g / zdiv, gh = g % zdiv;
  const unsigned short* Ab = A + (size_t)z * sAl + (size_t)gb * sAb + (size_t)gh * sAh;
  const unsigned short* Bb = B + (size_t)z * sBl + (size_t)gb * sBb + (size_t)gh * sBh;
  const int m0 = by * 128, n0 = bx * 128;
  const int t = threadIdx.x;
  const int lane = t & 63;
  const int wave = t >> 6;
  const int wm = wave >> 1, wn = wave & 1;

  const int sr2 = t >> 3;          // 0..31
  const int ss8 = t & 7;
  const int sq8 = ss8 ^ (sr2 & 7); // row&7 == sr2&7 (32 | 8)

  const unsigned short* ap0 = Ab + (size_t)(m0 +  0 + sr2) * ldA + sq8 * 8;
  const unsigned short* ap1 = Ab + (size_t)(m0 + 32 + sr2) * ldA + sq8 * 8;
  const unsigned short* ap2 = Ab + (size_t)(m0 + 64 + sr2) * ldA + sq8 * 8;
  const unsigned short* ap3 = Ab + (size_t)(m0 + 96 + sr2) * ldA + sq8 * 8;
  const unsigned short* bp0 = Bb + (size_t)(n0 +  0 + sr2) * ldB + sq8 * 8;
  const unsigned short* bp1 = Bb + (size_t)(n0 + 32 + sr2) * ldB + sq8 * 8;
  const unsigned short* bp2 = Bb + (size_t)(n0 + 64 + sr2) * ldB + sq8 * 8;
  const unsigned short* bp3 = Bb + (size_t)(n0 + 96 + sr2) * ldB + sq8 * 8;

  char* asd0 = (char*)As +     0 + t * 16;
  char* asd1 = (char*)As +  4096 + t * 16;
  char* asd2 = (char*)As +  8192 + t * 16;
  char* asd3 = (char*)As + 12288 + t * 16;
  char* bsd0 = (char*)Bs +     0 + t * 16;
  char* bsd1 = (char*)Bs +  4096 + t * 16;
  char* bsd2 = (char*)Bs +  8192 + t * 16;
  char* bsd3 = (char*)Bs + 12288 + t * 16;

  const int tq = lane & 15, qd = lane >> 4;

  f32x4 acc[4][4];
  #pragma unroll
  for (int i = 0; i < 4; ++i)
    #pragma unroll
    for (int j = 0; j < 4; ++j)
      acc[i][j] = f32x4{0.f, 0.f, 0.f, 0.f};

  const int kIters = K >> 6;
  for (int kt = 0; kt < kIters; ++kt) {
    __syncthreads();
    gl_lds16(ap0, asd0); gl_lds16(ap1, asd1);
    gl_lds16(ap2, asd2); gl_lds16(ap3, asd3);
    gl_lds16(bp0, bsd0); gl_lds16(bp1, bsd1);
    gl_lds16(bp2, bsd2); gl_lds16(bp3, bsd3);
    ap0 += 64; ap1 += 64; ap2 += 64; ap3 += 64;
    bp0 += 64; bp1 += 64; bp2 += 64; bp3 += 64;
    __builtin_amdgcn_s_waitcnt(0x0f70);    // vmcnt(0)
    __syncthreads();

    #pragma unroll
    for (int kk = 0; kk < 2; ++kk) {
      bf16x8 af[4], bfr[4];
      #pragma unroll
      for (int i = 0; i < 4; ++i) {
        const int R = wm * 64 + i * 16 + tq;
        const int slot = (kk * 4 + qd) ^ (R & 7);
        af[i] = *(const bf16x8*)(As + R * 64 + slot * 8);
      }
      #pragma unroll
      for (int j = 0; j < 4; ++j) {
        const int R = wn * 64 + j * 16 + tq;
        const int slot = (kk * 4 + qd) ^ (R & 7);
        bfr[j] = *(const bf16x8*)(Bs + R * 64 + slot * 8);
      }
      #pragma unroll
      for (int i = 0; i < 4; ++i)
        #pragma unroll
        for (int j = 0; j < 4; ++j)
          acc[i][j] = __builtin_amdgcn_mfma_f32_16x16x32_bf16(af[i], bfr[j], acc[i][j], 0, 0, 0);
    }
  }

  const size_t cOff = (size_t)z * sCl + (size_t)gb * sCb + (size_t)gh * sCh;
  #pragma unroll
  for (int i = 0; i < 4; ++i) {
    const int row = m0 + wm * 64 + i * 16 + qd * 4;   // C/D: row=(lane>>4)*4+reg
    #pragma unroll
    for (int j = 0; j < 4; ++j) {
      const int col = n0 + wn * 64 + j * 16 + tq;     // C/D: col=lane&15
      if constexpr (F32OUT) {
        float* C = (float*)Cv + cOff;
        #pragma unroll
        for (int rr = 0; rr < 4; ++rr)
          C[(size_t)(row + rr) * ldC + col] = acc[i][j][rr] * scale;
      } else {
        unsigned short* C = (unsigned short*)Cv + cOff;
        #pragma unroll
        for (int rr = 0; rr < 4; ++rr)
          C[(size_t)(row + rr) * ldC + col] = f2bf(acc[i][j][rr] * scale);
      }
    }
  }
}

// -------- pass 1: QK^T + exp + query-axis column sums; NO E store ----------
// colsum[bh][k] += sum_q exp(scale*Q.K + (1-mask[b,q])*NEG - 20)
__global__ __launch_bounds__(256) void gemm_scores_colsum(
    const unsigned short* __restrict__ QKV, float* __restrict__ colsum,
    const float* __restrict__ mask)
{
  __shared__ unsigned short sbuf[32768];   // 64 KB: As[128][128] | Bs[128][128]
  unsigned short* As = sbuf;
  unsigned short* Bs = sbuf + 16384;
  // chunked XCD swizzle over 4096 blocks: XCD i <- bh chunk [8i, 8i+8)
  int flat = blockIdx.x + 8 * (blockIdx.y + 8 * blockIdx.z);
  flat = (flat & 7) * 512 + (flat >> 3);
  const int bx = flat & 7, by = (flat >> 3) & 7, g = flat >> 6;
  const int b = g >> 3, h = g & 7;
  const unsigned short* Ab = QKV + (size_t)b * 3145728 + (size_t)h * 131072;
  const unsigned short* Bb = Ab + 1048576;
  const int m0 = by * 128, n0 = bx * 128;
  const int t = threadIdx.x;
  const int lane = t & 63;
  const int wave = t >> 6;
  const int wm = wave >> 1, wn = wave & 1;
  const int tq = lane & 15, qd = lane >> 4;

  const unsigned short* Aq = Ab + (size_t)m0 * 128;
  const unsigned short* Bk = Bb + (size_t)n0 * 128;
  #pragma unroll
  for (int it = 0; it < 8; ++it) {
    const int c = it * 256 + t;             // 0..2047
    const int row = c >> 4;
    const int src = (c ^ (c >> 4)) & 15;    // slot ^ (row&15)
    gl_lds16(Aq + (size_t)row * 128 + src * 8, (char*)As + c * 16);
    gl_lds16(Bk + (size_t)row * 128 + src * 8, (char*)Bs + c * 16);
  }
  __builtin_amdgcn_s_waitcnt(0x0f70);    // vmcnt(0)
  __syncthreads();

  f32x4 acc[4][4];
  #pragma unroll
  for (int i = 0; i < 4; ++i)
    #pragma unroll
    for (int j = 0; j < 4; ++j)
      acc[i][j] = f32x4{0.f, 0.f, 0.f, 0.f};

  #pragma unroll
  for (int kk = 0; kk < 4; ++kk) {
    bf16x8 af[4], bfr[4];
    #pragma unroll
    for (int i = 0; i < 4; ++i) {
      const int R = wm * 64 + i * 16 + tq;
      const int slot = (kk * 4 + qd) ^ (R & 15);
      af[i] = *(const bf16x8*)(As + R * 128 + slot * 8);
    }
    #pragma unroll
    for (int j = 0; j < 4; ++j) {
      const int R = wn * 64 + j * 16 + tq;
      const int slot = (kk * 4 + qd) ^ (R & 15);
      bfr[j] = *(const bf16x8*)(Bs + R * 128 + slot * 8);
    }
    #pragma unroll
    for (int i = 0; i < 4; ++i)
      #pragma unroll
      for (int j = 0; j < 4; ++j)
        acc[i][j] = __builtin_amdgcn_mfma_f32_16x16x32_bf16(af[i], bfr[j], acc[i][j], 0, 0, 0);
  }

  float* cs = colsum + (size_t)g * 1024;
  const float scl = 0.08838834764831845f;  // 1/sqrt(128)
  const float* mrow = mask + (size_t)b * 1024;

  float cp[4] = {0.f, 0.f, 0.f, 0.f};   // per-j partial column sums
  #pragma unroll
  for (int i = 0; i < 4; ++i) {
    const int r0 = wm * 64 + i * 16 + qd * 4;
    const float4 m4 = *(const float4*)(mrow + m0 + r0);
    const float aq[4] = {(1.f - m4.x) * MASK_NEG - 20.f, (1.f - m4.y) * MASK_NEG - 20.f,
                         (1.f - m4.z) * MASK_NEG - 20.f, (1.f - m4.w) * MASK_NEG - 20.f};
    #pragma unroll
    for (int rr = 0; rr < 4; ++rr) {
      #pragma unroll
      for (int j = 0; j < 4; ++j) {
        const float e = __expf(acc[i][j][rr] * scl + aq[rr]);
        cp[j] += e;
      }
    }
  }
  #pragma unroll
  for (int j = 0; j < 4; ++j) {
    float v = cp[j];
    v += __shfl_xor(v, 16, 64);
    v += __shfl_xor(v, 32, 64);
    if (qd == 0)
      atomicAdd(&cs[n0 + wn * 64 + j * 16 + tq], v);
  }
}

// -------- transpose V [l][dv] -> V' [dv][l], scaled by 1/colsum[l] --------
__global__ __launch_bounds__(256) void tvscale(
    const unsigned short* __restrict__ QKV, unsigned short* __restrict__ Vp,
    const float* __restrict__ colsum)
{
  __shared__ unsigned short tile[64][72];
  const int g = blockIdx.z;
  const int b = g >> 3, h = g & 7;
  const unsigned short* S = QKV + (size_t)b * 3145728 + (size_t)(16 + h) * 131072;
  unsigned short* D = Vp + (size_t)g * 131072;
  const float* cs = colsum + (size_t)g * 1024;
  const int l0 = blockIdx.x * 64;   // 16 tiles
  const int d0 = blockIdx.y * 64;   // 2 tiles
  const int t = threadIdx.x;
  {
    const int r = t >> 4, c4 = (t & 15) * 4;
    for (int it = 0; it < 4; ++it) {
      const int rr = r + it * 16;
      const ushort4 v = *(const ushort4*)(S + (size_t)(l0 + rr) * 128 + d0 + c4);
      *(ushort4*)&tile[rr][c4] = v;
    }
  }
  __syncthreads();
  {
    const int cc = t >> 4, r4 = (t & 15) * 4;
    const float4 c4v = *(const float4*)(cs + l0 + r4);
    for (int it = 0; it < 4; ++it) {
      const int c = cc + it * 16;   // dv
      ushort4 o;
      o.x = f2bf(bf2f(tile[r4 + 0][c]) / c4v.x);
      o.y = f2bf(bf2f(tile[r4 + 1][c]) / c4v.y);
      o.z = f2bf(bf2f(tile[r4 + 2][c]) / c4v.z);
      o.w = f2bf(bf2f(tile[r4 + 3][c]) / c4v.w);
      *(ushort4*)(D + (size_t)(d0 + c) * 1024 + l0 + r4) = o;
    }
  }
}

// -------- pass 2: fused scores-recompute + P*V' accumulation ---------------
// Per block: one (bh, q-tile of 128). Q-frags resident in VGPRs; loop over
// 16 k-tiles of 64: stage K/V' -> S=QK^T -> exp -> P in LDS -> H += P*V'^T.
// E (bit-compatible with pass 1) never touches HBM.
__global__ __launch_bounds__(256, 2) void attn_pv_fused(
    const unsigned short* __restrict__ QKV, const unsigned short* __restrict__ Vp,
    unsigned short* __restrict__ Hp, const float* __restrict__ mask)
{
  __shared__ unsigned short lds[32768];   // 64 KB
  unsigned short* Qs = lds;               // [128][128] 16-slot swz (prologue)
  unsigned short* Ps = lds;               // [128][64]  8-slot swz (overlays Qs)
  unsigned short* Ks = lds + 16384;       // [64][128]  16-slot swz
  unsigned short* Vs = lds + 24576;       // [128][64]  8-slot swz

  // chunked XCD swizzle over 512 blocks: XCD i <- bh chunk [8i, 8i+8)
  const int bid = blockIdx.x;
  const int w = ((bid & 7) << 6) | (bid >> 3);
  const int g = w >> 3, qx = w & 7;
  const int b = g >> 3, h = g & 7;
  const unsigned short* Qg = QKV + (size_t)b * 3145728 + (size_t)h * 131072
                                 + (size_t)qx * 16384;
  const unsigned short* Kg = QKV + (size_t)b * 3145728 + (size_t)(8 + h) * 131072;
  const unsigned short* Vg = Vp + (size_t)g * 131072;

  const int t = threadIdx.x;
  const int lane = t & 63, wave = t >> 6;
  const int wm = wave >> 1, wn = wave & 1;
  const int tq = lane & 15, qd = lane >> 4;

  // ---- prologue: stage Q tile, lift Q-frags to registers ----
  #pragma unroll
  for (int it = 0; it < 8; ++it) {
    const int c = it * 256 + t;             // 0..2047
    const int row = c >> 4;
    const int src = (c ^ (c >> 4)) & 15;
    gl_lds16(Qg + (size_t)row * 128 + src * 8, (char*)Qs + c * 16);
  }
  __builtin_amdgcn_s_waitcnt(0x0f70);    // vmcnt(0)
  __syncthreads();

  bf16x8 qf[4][4];
  #pragma unroll
  for (int i = 0; i < 4; ++i) {
    const int R = wm * 64 + i * 16 + tq;
    #pragma unroll
    for (int kk = 0; kk < 4; ++kk)
      qf[i][kk] = *(const bf16x8*)(Qs + R * 128 + (((kk * 4 + qd) ^ (R & 15)) * 8));
  }
  __syncthreads();   // Qs reads done; region becomes Ps

  f32x4 acc_h[4][4];
  #pragma unroll
  for (int i = 0; i < 4; ++i)
    #pragma unroll
    for (int j = 0; j < 4; ++j)
      acc_h[i][j] = f32x4{0.f, 0.f, 0.f, 0.f};

  const float scl = 0.08838834764831845f;  // 1/sqrt(128)
  float aq[4][4];
  {
    const float* mrow = mask + (size_t)b * 1024 + qx * 128;
    #pragma unroll
    for (int i = 0; i < 4; ++i) {
      const float4 m4 = *(const float4*)(mrow + wm * 64 + i * 16 + qd * 4);
      aq[i][0] = (1.f - m4.x) * MASK_NEG - 20.f;
      aq[i][1] = (1.f - m4.y) * MASK_NEG - 20.f;
      aq[i][2] = (1.f - m4.z) * MASK_NEG - 20.f;
      aq[i][3] = (1.f - m4.w) * MASK_NEG - 20.f;
    }
  }

  for (int kt = 0; kt < 16; ++kt) {
    __syncthreads();   // prev tile's P/K/V reads complete
    #pragma unroll
    for (int it = 0; it < 4; ++it) {
      const int c = it * 256 + t;           // K: 1024 chunks, [64][128] 16-slot
      const int row = c >> 4;
      const int src = (c ^ (c >> 4)) & 15;
      gl_lds16(Kg + (size_t)(kt * 64 + row) * 128 + src * 8, (char*)Ks + c * 16);
    }
    #pragma unroll
    for (int it = 0; it < 4; ++it) {
      const int c = it * 256 + t;           // V': 1024 chunks, [128][64] 8-slot
      const int row = c >> 3;
      const int src = (c ^ (c >> 3)) & 7;
      gl_lds16(Vg + (size_t)row * 1024 + kt * 64 + src * 8, (char*)Vs + c * 16);
    }
    __builtin_amdgcn_s_waitcnt(0x0f70);    // vmcnt(0)
    __syncthreads();

    // ---- S = Q * K^T : per-wave quadrant [64 q][32 k] ----
    f32x4 acc_s[4][2];
    #pragma unroll
    for (int i = 0; i < 4; ++i)
      #pragma unroll
      for (int j = 0; j < 2; ++j)
        acc_s[i][j] = f32x4{0.f, 0.f, 0.f, 0.f};
    #pragma unroll
    for (int kk = 0; kk < 4; ++kk) {
      bf16x8 kf[2];
      #pragma unroll
      for (int j = 0; j < 2; ++j) {
        const int R = wn * 32 + j * 16 + tq;
        kf[j] = *(const bf16x8*)(Ks + R * 128 + (((kk * 4 + qd) ^ (R & 15)) * 8));
      }
      #pragma unroll
      for (int i = 0; i < 4; ++i)
        #pragma unroll
        for (int j = 0; j < 2; ++j)
          acc_s[i][j] = __builtin_amdgcn_mfma_f32_16x16x32_bf16(qf[i][kk], kf[j], acc_s[i][j], 0, 0, 0);
    }

    // ---- exp + additive mask -> P (bf16, LDS, 8-slot swizzle) ----
    #pragma unroll
    for (int i = 0; i < 4; ++i) {
      const int q0 = wm * 64 + i * 16 + qd * 4;
      #pragma unroll
      for (int rr = 0; rr < 4; ++rr) {
        const int q = q0 + rr;
        #pragma unroll
        for (int j = 0; j < 2; ++j) {
          const int kl = wn * 32 + j * 16 + tq;
          const float e = __expf(acc_s[i][j][rr] * scl + aq[i][rr]);
          Ps[q * 64 + ((((kl >> 3) ^ (q & 7)) * 8) | (kl & 7))] = f2bf(e);
        }
      }
    }
    __syncthreads();

    // ---- H += P * V'^T : per-wave quadrant [64 q][64 dv], contraction 64 ----
    #pragma unroll
    for (int k2 = 0; k2 < 2; ++k2) {
      bf16x8 pf[4], vf[4];
      #pragma unroll
      for (int i = 0; i < 4; ++i) {
        const int R = wm * 64 + i * 16 + tq;
        pf[i] = *(const bf16x8*)(Ps + R * 64 + (((k2 * 4 + qd) ^ (R & 7)) * 8));
      }
      #pragma unroll
      for (int j = 0; j < 4; ++j) {
        const int R = wn * 64 + j * 16 + tq;
        vf[j] = *(const bf16x8*)(Vs + R * 64 + (((k2 * 4 + qd) ^ (R & 7)) * 8));
      }
      #pragma unroll
      for (int i = 0; i < 4; ++i)
        #pragma unroll
        for (int j = 0; j < 4; ++j)
          acc_h[i][j] = __builtin_amdgcn_mfma_f32_16x16x32_bf16(pf[i], vf[j], acc_h[i][j], 0, 0, 0);
    }
  }

  // ---- epilogue: Hp[b][qx*128 + q][h*128 + dv] ----
  unsigned short* Hb = Hp + (size_t)b * 1048576 + (size_t)qx * 131072 + h * 128;
  #pragma unroll
  for (int i = 0; i < 4; ++i) {
    const int q0 = wm * 64 + i * 16 + qd * 4;
    #pragma unroll
    for (int j = 0; j < 4; ++j) {
      const int dv = wn * 64 + j * 16 + tq;
      #pragma unroll
      for (int rr = 0; rr < 4; ++rr)
        Hb[(size_t)(q0 + rr) * 1024 + dv] = f2bf(acc_h[i][j][rr]);
    }
  }
}

extern "C" void kernel_launch(void* const* d_in, const int* in_sizes, int n_in,
                              void* d_out, int out_size, void* d_ws, size_t ws_size,
                              hipStream_t stream) {
  const float* x    = (const float*)d_in[0];   // [8,1024,1024]  (B,D,L)
  const float* mask = (const float*)d_in[1];   // [8,1024]
  const float* Wq   = (const float*)d_in[2];   // [8,1024,128]
  const float* Wk   = (const float*)d_in[3];
  const float* Wv   = (const float*)d_in[4];
  const float* Wo   = (const float*)d_in[5];   // [1024,1024]
  float* out = (float*)d_out;                  // [8,1024,1024]  (B,D,L)

  char* p = (char*)d_ws;
  unsigned short* xt    = (unsigned short*)p; p += 16777216;  // [b][l][d] bf16
  unsigned short* WqkvT = (unsigned short*)p; p += 6291456;   // [24 heads][128][1024]
  unsigned short* Wot   = (unsigned short*)p; p += 2097152;   // [j][i]
  unsigned short* QKV   = (unsigned short*)p; p += 50331648;  // [b][24h][l][128]
  unsigned short* Vp    = (unsigned short*)p; p += 16777216;  // [b][h][dv][k]
  unsigned short* Hp    = (unsigned short*)p; p += 16777216;  // [b][l][h*128+dv]
  float* colsum = (float*)p; p += 262144;                     // [64][1024] fp32

  hipMemsetAsync(colsum, 0, 262144, stream);

  // prologue: transposes
  transpose_x_wo<<<dim3(16, 16, 9), 256, 0, stream>>>(x, Wo, xt, Wot);
  transpose_w24<<<dim3(2, 16, 24), 256, 0, stream>>>(Wq, Wk, Wv, WqkvT);

  // QKV[b][gh][l][dk] = xt[b] * WqkvT[gh]^T   (z=192: gb=b, gh=0..23)
  gemm_tn<false><<<dim3(1, 8, 192), 256, 0, stream>>>(
      xt, WqkvT, (void*)QKV, 1024, 1024, 1024, 128, 1.f,
      0L, 1048576L, 0L,  0L, 0L, 131072L,  0L, 3145728L, 131072L, 0, 24);

  // pass 1: colsum only (no E materialization)
  gemm_scores_colsum<<<dim3(8, 8, 64), 256, 0, stream>>>(QKV, colsum, mask);

  // V' = V^T / colsum
  tvscale<<<dim3(16, 2, 64), 256, 0, stream>>>(QKV, Vp, colsum);

  // pass 2: fused scores-recompute + PV, H[b][q][h*128+dv]
  attn_pv_fused<<<dim3(512, 1, 1), 256, 0, stream>>>(QKV, Vp, Hp, mask);

  // out[b][j][l] = Wot[j,:] . H[b][l,:]   (M=1024 j, N=1024 l, K=1024 i)
  gemm_tn<true><<<dim3(8, 8, 8), 256, 0, stream>>>(
      Wot, Hp, (void*)out, 1024, 1024, 1024, 1024, 1.f,
      0L, 0L, 0L,  0L, 1048576L, 0L,  0L, 1048576L, 0L, 0, 1);
}